// Round 14
// baseline (78.497 us; speedup 1.0000x reference)
//
#include <hip/hip_runtime.h>

// deltaE (CIEDE2000) color loss: mean over 32x512x512 pixels.
// Reference reshapes (B,3,H,W)->(B,H,W,3) WITHOUT transpose => each pixel's
// RGB is 3 consecutive floats. 4 px/item = 3 float4 loads per image.
//
// Round-14: r11 structure (best, 57.7us) + trans elimination in rgb2lab.
// Measured cost model (r11 busy reconciliation): scalar trans = ~16cy/wave64
// -> 76 trans/de2 = 78% of issue. Replace log2/exp2 pairs with division-free
// Newton from bit-hack seeds, fully packed:
//   cbrt(t) = t*y^2,  y=t^(-1/3):  y <- y*(4/3 - t*y^3/3)   (2 iters)
//   u^2.4  = u^3*y^3, y=u^(-1/5):  y <- y*(6/5 - u*y^5/5)   (2 iters)
// Seeds ~3-5% err, quadratic convergence -> ~1e-4 rel; threshold 0.895.

__device__ __forceinline__ float fexp2(float x) { return __builtin_amdgcn_exp2f(x); }
__device__ __forceinline__ float frcp(float x)  { return __builtin_amdgcn_rcpf(x); }
__device__ __forceinline__ float fsqrt_(float x){ return __builtin_amdgcn_sqrtf(x); }
__device__ __forceinline__ float frsq(float x)  { return __builtin_amdgcn_rsqf(x); }

// ---- native 2-wide float vector ---------------------------------------------
typedef float F2 __attribute__((ext_vector_type(2)));

__device__ __forceinline__ F2 mk2(float a, float b) { F2 r; r.x = a; r.y = b; return r; }
__device__ __forceinline__ F2 sp(float s) { F2 r; r.x = s; r.y = s; return r; }

__device__ __forceinline__ F2 vfma(F2 a, F2 b, F2 c) { return __builtin_elementwise_fma(a, b, c); }
__device__ __forceinline__ F2 vfma(float a, F2 b, F2 c) { return __builtin_elementwise_fma(sp(a), b, c); }
__device__ __forceinline__ F2 vfma(F2 a, float b, F2 c) { return __builtin_elementwise_fma(a, sp(b), c); }
__device__ __forceinline__ F2 vmaxs(F2 a, float s) { return __builtin_elementwise_max(a, sp(s)); }

__device__ __forceinline__ F2 vsqrt(F2 a) { F2 r; r.x = fsqrt_(a.x); r.y = fsqrt_(a.y); return r; }
__device__ __forceinline__ F2 vrcp(F2 a)  { F2 r; r.x = frcp(a.x);  r.y = frcp(a.y);  return r; }
__device__ __forceinline__ F2 vrsq(F2 a)  { F2 r; r.x = frsq(a.x);  r.y = frsq(a.y);  return r; }
__device__ __forceinline__ F2 vexp2(F2 a) { F2 r; r.x = fexp2(a.x); r.y = fexp2(a.y); return r; }
__device__ __forceinline__ F2 vcopysign(F2 a, F2 s) {
    F2 r; r.x = copysignf(a.x, s.x); r.y = copysignf(a.y, s.y); return r;
}

__device__ __forceinline__ F2 vpow7(F2 x) {
    F2 x2 = x * x;
    F2 x3 = x2 * x;
    return x3 * x3 * x;
}

// t^(1/3), t >= 0 (used only for t > 0.008856; returns 0 at t=0 harmlessly).
// y = t^(-1/3) via bit-hack seed + 2 division-free Newton; cbrt = t*y^2.
__device__ __forceinline__ F2 vcbrt_nt(F2 t) {
    F2 y;
    y.x = __uint_as_float(0x54A2FA8Du - __float_as_uint(t.x) / 3u);
    y.y = __uint_as_float(0x54A2FA8Du - __float_as_uint(t.y) / 3u);
    F2 y3 = y * y * y;
    y = y * vfma(t * y3, -(1.0f / 3.0f), sp(4.0f / 3.0f));
    y3 = y * y * y;
    y = y * vfma(t * y3, -(1.0f / 3.0f), sp(4.0f / 3.0f));
    return t * (y * y);
}

// u^2.4 for u in [0.05, 1]: y = u^(-1/5) via seed + 2 Newton; u^2.4 = u^3*y^3.
__device__ __forceinline__ F2 vpow24(F2 u) {
    F2 y;
    y.x = __uint_as_float(0x4C2C47E6u - __float_as_uint(u.x) / 5u);
    y.y = __uint_as_float(0x4C2C47E6u - __float_as_uint(u.y) / 5u);
    F2 y2 = y * y;
    F2 y5 = y2 * y2 * y;
    y = y * vfma(u * y5, -0.2f, sp(1.2f));
    y2 = y * y;
    y5 = y2 * y2 * y;
    y = y * vfma(u * y5, -0.2f, sp(1.2f));
    F2 u3 = u * u * u;
    F2 y3 = y * y * y;
    return u3 * y3;
}

__device__ __forceinline__ F2 vsrgb(F2 v) {
    F2 u = (v + 0.055f) * (1.0f / 1.055f);
    F2 p = vpow24(u);
    F2 lo = v * (1.0f / 12.92f);
    F2 r;
    r.x = (v.x <= 0.04045f) ? lo.x : p.x;
    r.y = (v.y <= 0.04045f) ? lo.y : p.y;
    return r;
}

__device__ __forceinline__ F2 vfxyz(F2 t) {
    F2 c = vcbrt_nt(t);
    F2 lo = vfma(t, 7.787f, sp(16.0f / 116.0f));
    F2 r;
    r.x = (t.x > 0.008856f) ? c.x : lo.x;
    r.y = (t.y > 0.008856f) ? c.y : lo.y;
    return r;
}

__device__ __forceinline__ void rgb2lab2(F2 r, F2 g, F2 b,
                                         F2& L, F2& A, F2& B) {
    F2 rl = vsrgb(r), gl = vsrgb(g), bl = vsrgb(b);
    // white point folded into matrix rows (x/0.95047, z/1.08883)
    F2 x = vfma(0.43395296f, rl, vfma(0.37621626f, gl, 0.18982646f * bl));
    F2 y = vfma(0.212671f,  rl, vfma(0.715160f,  gl, 0.072169f  * bl));
    F2 z = vfma(0.017757f,  rl, vfma(0.10946953f, gl, 0.87271810f * bl));
    F2 fx = vfxyz(x), fy = vfxyz(y), fz = vfxyz(z);
    L = vfma(116.0f, fy, sp(-16.0f));
    A = 500.0f * (fx - fy);
    B = 200.0f * (fy - fz);
}

// CIEDE2000 for two pixel-pairs in lockstep; returns dE.x + dE.y
__device__ __forceinline__ float ciede2(F2 L1, F2 a1, F2 b1,
                                        F2 L2, F2 a2, F2 b2) {
    const float P25_7 = 6103515625.0f;        // 25^7

    F2 b1sq = b1 * b1, b2sq = b2 * b2;
    F2 C1 = vsqrt(vfma(a1, a1, b1sq));
    F2 C2 = vsqrt(vfma(a2, a2, b2sq));
    F2 Cbar = 0.5f * (C1 + C2);
    F2 c7 = vpow7(Cbar);
    F2 G1 = sp(1.5f) - 0.5f * vsqrt(c7 * vrcp(c7 + P25_7));   // 1+G
    F2 a1p = a1 * G1;
    F2 a2p = a2 * G1;
    F2 C1p = vsqrt(vfma(a1p, a1p, b1sq));
    F2 C2p = vsqrt(vfma(a2p, a2p, b2sq));
    F2 CC  = C1p * C2p;

    // dHp = sign(cross)*sqrt(2*(CC - dot)); dot/cross from vector identity
    F2 dot   = vfma(a1p, a2p, b1 * b2);
    F2 cross = vfma(b2, a1p, -(a2p * b1));
    F2 dHp = vcopysign(vsqrt(vmaxs(2.0f * (CC - dot), 0.0f)), cross);

    F2 dLp = L2 - L1;
    F2 dCp = C2p - C1p;

    // hbar bisector = normalize(u1*C2p + u2*C1p); CC==0 cases are no-ops
    // (dHp=0 => tH=0 kills all hbar-dependent terms).
    F2 sx = vfma(a1p, C2p, a2p * C1p);
    F2 sy = vfma(b1,  C2p, b2  * C1p);
    F2 n2 = vfma(sx, sx, sy * sy);
    F2 inv;
    inv.x = (n2.x > 0.0f) ? frsq(n2.x) : 0.0f;
    inv.y = (n2.y > 0.0f) ? frsq(n2.y) : 0.0f;
    F2 ch = sx * inv, sh = sy * inv;          // cos(hbar), sin(hbar)

    // T by angle addition — no trig
    F2 c2v = vfma(2.0f * ch, ch, sp(-1.0f));
    F2 s2v = 2.0f * sh * ch;
    F2 c3v = vfma(c2v, ch, -(s2v * sh));
    F2 s3v = vfma(s2v, ch, c2v * sh);
    F2 c4v = vfma(2.0f * c2v, c2v, sp(-1.0f));
    F2 s4v = 2.0f * s2v * c2v;
    F2 T = sp(1.0f) - 0.17f * vfma(ch, 0.8660254037844387f, sh * 0.5f)
         + 0.24f * c2v
         + 0.32f * vfma(c3v, 0.9945218953682733f, s3v * (-0.10452846326765347f))
         - 0.20f * vfma(c4v, 0.45399049973954675f, s4v * 0.8910065241883679f);

    // Gaussian angle: td^2 = (phi_deg/25)^2 via asin^2 series in u2 (no sqrt)
    const float C275 = 0.08715574f, S275 = -0.9961947f;
    F2 cphi = vfma(ch, C275, sh * S275);          // cos(hbar - 275deg)
    F2 u2 = vmaxs(vfma(cphi, -0.5f, sp(0.5f)), 0.0f);
    F2 ser = vfma(u2, vfma(u2, vfma(u2, sp(0.11428571f), sp(0.17777778f)),
                           sp(0.33333333f)), sp(1.0f));
    F2 td2 = 21.00996f * (u2 * ser);               // (4.5836624^2)*asin^2(u)
    F2 dtheta = 30.0f * vexp2(-1.4426950408889634f * td2);

    F2 Lbar  = 0.5f * (L1 + L2);
    F2 Cbarp = 0.5f * (C1p + C2p);
    F2 Lm50 = Lbar - 50.0f;
    F2 q = Lm50 * Lm50;
    F2 Sl = vfma(0.015f * q, vrsq(q + 20.0f), sp(1.0f));
    F2 Sc = vfma(0.045f, Cbarp, sp(1.0f));
    F2 Sh = vfma(0.015f * Cbarp, T, sp(1.0f));

    F2 cb7 = vpow7(Cbarp);
    F2 Rc = 2.0f * vsqrt(cb7 * vrcp(cb7 + P25_7));
    // sin(2*dtheta deg): arg <= 1.047 rad; odd poly deg-5
    F2 xr = 0.034906585f * dtheta;
    F2 xr2 = xr * xr;
    F2 sin2dt = xr * vfma(xr2, vfma(xr2, sp(8.3333338e-3f), sp(-1.6666667e-1f)),
                          sp(1.0f));
    F2 Rt = -(Rc * sin2dt);

    F2 ScSh = Sc * Sh;
    F2 R3 = vrcp(Sl * ScSh);
    F2 tL = dLp * ScSh * R3;
    F2 tC = dCp * (Sl * Sh) * R3;
    F2 tH = dHp * (Sl * Sc) * R3;
    F2 s = vfma(tL, tL, vfma(tC, tC, vfma(tH, tH, Rt * tC * tH)));
    F2 dE = vsqrt(vmaxs(s, 0.0f));
    return fabsf(dE.x) + fabsf(dE.y);
}

// two pixel-pairs -> sum of their dE
__device__ __forceinline__ float de2(F2 gr, F2 gg, F2 gb,
                                     F2 rr, F2 rg, F2 rb) {
    F2 L1, A1, B1, L2, A2, B2;
    rgb2lab2(rr, rg, rb, L1, A1, B1);   // gt
    rgb2lab2(gr, gg, gb, L2, A2, B2);   // gen
    return ciede2(L1, A1, B1, L2, A2, B2);
}

// 4 pixels from 3 float4s per image: two lockstep pairs.
__device__ __forceinline__ float process4(const float4& g0, const float4& g1,
                                          const float4& g2, const float4& r0,
                                          const float4& r1, const float4& r2) {
    float acc;
    acc  = de2(mk2(g0.x, g0.w), mk2(g0.y, g1.x), mk2(g0.z, g1.y),
               mk2(r0.x, r0.w), mk2(r0.y, r1.x), mk2(r0.z, r1.y));
    acc += de2(mk2(g1.z, g2.y), mk2(g1.w, g2.z), mk2(g2.x, g2.w),
               mk2(r1.z, r2.y), mk2(r1.w, r2.z), mk2(r2.x, r2.w));
    return acc;
}

__device__ __forceinline__ void block_reduce_store(float acc, float* dst) {
    for (int off = 32; off > 0; off >>= 1) acc += __shfl_down(acc, off, 64);
    __shared__ float sm[4];
    int lane = threadIdx.x & 63;
    int wid  = threadIdx.x >> 6;
    if (lane == 0) sm[wid] = acc;
    __syncthreads();
    if (threadIdx.x == 0) *dst = sm[0] + sm[1] + sm[2] + sm[3];
}

// Exact-trip looped kernel, 1-deep register prefetch, waves_per_eu(2,4)
// (r11 optimum structure).
template <int NITER>
__global__ __attribute__((amdgpu_waves_per_eu(2, 4)))
__launch_bounds__(256) void de_main_fix(const float4* __restrict__ gen,
                                        const float4* __restrict__ gt,
                                        float* __restrict__ partial,
                                        int stride) {
    int t = blockIdx.x * 256 + threadIdx.x;
    float acc = 0.0f;

    float4 cg0 = gen[3 * t + 0], cg1 = gen[3 * t + 1], cg2 = gen[3 * t + 2];
    float4 cr0 = gt [3 * t + 0], cr1 = gt [3 * t + 1], cr2 = gt [3 * t + 2];

    #pragma unroll 1
    for (int it = 0; it < NITER - 1; ++it) {
        int tn = t + stride;
        float4 ng0 = gen[3 * tn + 0], ng1 = gen[3 * tn + 1], ng2 = gen[3 * tn + 2];
        float4 nr0 = gt [3 * tn + 0], nr1 = gt [3 * tn + 1], nr2 = gt [3 * tn + 2];
        acc += process4(cg0, cg1, cg2, cr0, cr1, cr2);
        cg0 = ng0; cg1 = ng1; cg2 = ng2;
        cr0 = nr0; cr1 = nr1; cr2 = nr2;
        t = tn;
    }
    acc += process4(cg0, cg1, cg2, cr0, cr1, cr2);

    block_reduce_store(acc, &partial[blockIdx.x]);
}

// Generic fallback (bounds-checked grid-stride), used only if sizes change.
__global__ __launch_bounds__(256) void de_main_gen(const float4* __restrict__ gen,
                                                   const float4* __restrict__ gt,
                                                   float* __restrict__ partial,
                                                   int ntrip) {
    int tid = blockIdx.x * blockDim.x + threadIdx.x;
    int stride = gridDim.x * blockDim.x;
    float acc = 0.0f;
    for (int t = tid; t < ntrip; t += stride) {
        float4 g0 = gen[3 * t + 0], g1 = gen[3 * t + 1], g2 = gen[3 * t + 2];
        float4 r0 = gt [3 * t + 0], r1 = gt [3 * t + 1], r2 = gt [3 * t + 2];
        acc += process4(g0, g1, g2, r0, r1, r2);
    }
    block_reduce_store(acc, &partial[blockIdx.x]);
}

__global__ __launch_bounds__(256) void de_final(const float* __restrict__ partial,
                                                float* __restrict__ out,
                                                int n, float inv_npix) {
    float acc = 0.0f;
    for (int i = threadIdx.x; i < n; i += 256) acc += partial[i];
    for (int off = 32; off > 0; off >>= 1) acc += __shfl_down(acc, off, 64);
    __shared__ float sm[4];
    int lane = threadIdx.x & 63;
    int wid  = threadIdx.x >> 6;
    if (lane == 0) sm[wid] = acc;
    __syncthreads();
    if (threadIdx.x == 0) out[0] = (sm[0] + sm[1] + sm[2] + sm[3]) * inv_npix;
}

extern "C" void kernel_launch(void* const* d_in, const int* in_sizes, int n_in,
                              void* d_out, int out_size, void* d_ws, size_t ws_size,
                              hipStream_t stream) {
    const float4* gen = (const float4*)d_in[0];  // genImage
    const float4* gt  = (const float4*)d_in[1];  // gtImage

    const int total_f = in_sizes[0];             // 25,165,824 floats
    const int ntrip   = total_f / 12;            // 4-pixel work items
    const int npix    = total_f / 3;

    float* partial = (float*)d_ws;
    const int blocks  = 2048;
    const int threads = blocks * 256;

    if (ntrip == threads * 4) {
        de_main_fix<4><<<blocks, 256, 0, stream>>>(gen, gt, partial, threads);
        de_final<<<1, 256, 0, stream>>>(partial, (float*)d_out,
                                        blocks, 1.0f / (float)npix);
    } else {
        de_main_gen<<<blocks, 256, 0, stream>>>(gen, gt, partial, ntrip);
        de_final<<<1, 256, 0, stream>>>(partial, (float*)d_out,
                                        blocks, 1.0f / (float)npix);
    }
}

// Round 15
// 57.533 us; speedup vs baseline: 1.3644x; 1.3644x over previous
//
#include <hip/hip_runtime.h>

// deltaE (CIEDE2000) color loss: mean over 32x512x512 pixels.
// Reference reshapes (B,3,H,W)->(B,H,W,3) WITHOUT transpose => each pixel's
// RGB is 3 consecutive floats. 4 px/item = 3 float4 loads per image.
//
// Round-15: r11 config (best, 57.7us) + strictly-issue-reducing cuts.
// r14 established trans issue ~= VALU rate (T~2.7cy, not 16): Newton swap
// added issue. Cuts here: (1) sqrt(x/(x+K)) -> x*rsq(x^2+Kx) for G and Rc
// (-2 rcp each, exact identity); (2) n2 guard via max() not selects;
// (3) both rgb2lab2 calls fused+batched (scheduler no-op at worst).

__device__ __forceinline__ float fexp2(float x) { return __builtin_amdgcn_exp2f(x); }
__device__ __forceinline__ float flog2(float x) { return __builtin_amdgcn_logf(x); }
__device__ __forceinline__ float frcp(float x)  { return __builtin_amdgcn_rcpf(x); }
__device__ __forceinline__ float fsqrt_(float x){ return __builtin_amdgcn_sqrtf(x); }
__device__ __forceinline__ float frsq(float x)  { return __builtin_amdgcn_rsqf(x); }

// ---- native 2-wide float vector ---------------------------------------------
typedef float F2 __attribute__((ext_vector_type(2)));

__device__ __forceinline__ F2 mk2(float a, float b) { F2 r; r.x = a; r.y = b; return r; }
__device__ __forceinline__ F2 sp(float s) { F2 r; r.x = s; r.y = s; return r; }

__device__ __forceinline__ F2 vfma(F2 a, F2 b, F2 c) { return __builtin_elementwise_fma(a, b, c); }
__device__ __forceinline__ F2 vfma(float a, F2 b, F2 c) { return __builtin_elementwise_fma(sp(a), b, c); }
__device__ __forceinline__ F2 vfma(F2 a, float b, F2 c) { return __builtin_elementwise_fma(a, sp(b), c); }
__device__ __forceinline__ F2 vmaxs(F2 a, float s) { return __builtin_elementwise_max(a, sp(s)); }

__device__ __forceinline__ F2 vsqrt(F2 a) { F2 r; r.x = fsqrt_(a.x); r.y = fsqrt_(a.y); return r; }
__device__ __forceinline__ F2 vrcp(F2 a)  { F2 r; r.x = frcp(a.x);  r.y = frcp(a.y);  return r; }
__device__ __forceinline__ F2 vrsq(F2 a)  { F2 r; r.x = frsq(a.x);  r.y = frsq(a.y);  return r; }
__device__ __forceinline__ F2 vexp2(F2 a) { F2 r; r.x = fexp2(a.x); r.y = fexp2(a.y); return r; }
__device__ __forceinline__ F2 vlog2(F2 a) { F2 r; r.x = flog2(a.x); r.y = flog2(a.y); return r; }
__device__ __forceinline__ F2 vcopysign(F2 a, F2 s) {
    F2 r; r.x = copysignf(a.x, s.x); r.y = copysignf(a.y, s.y); return r;
}

__device__ __forceinline__ F2 vpow7(F2 x) {
    F2 x2 = x * x;
    F2 x3 = x2 * x;
    return x3 * x3 * x;
}

// sqrt(x/(x+K)) = x * rsq(x^2 + K*x), guarded for x=0 by +1e-20.
__device__ __forceinline__ F2 vsqrt_ratio7(F2 x, float K) {
    F2 t = vfma(x, x, vfma(x, K, sp(1e-20f)));
    return x * vrsq(t);
}

__device__ __forceinline__ F2 vsrgb(F2 v) {
    F2 u = (v + 0.055f) * (1.0f / 1.055f);
    F2 p = vexp2(2.4f * vlog2(u));
    F2 lo = v * (1.0f / 12.92f);
    F2 r;
    r.x = (v.x <= 0.04045f) ? lo.x : p.x;
    r.y = (v.y <= 0.04045f) ? lo.y : p.y;
    return r;
}

__device__ __forceinline__ F2 vfxyz(F2 t) {
    F2 c = vexp2(0.3333333333333333f * vlog2(t));
    F2 lo = vfma(t, 7.787f, sp(16.0f / 116.0f));
    F2 r;
    r.x = (t.x > 0.008856f) ? c.x : lo.x;
    r.y = (t.y > 0.008856f) ? c.y : lo.y;
    return r;
}

// Both images' lab conversions fused: all 6 sRGB linearizations issued
// together, then both matrix transforms, then all 6 cbrt-f's together —
// maximizes independent trans in flight.
__device__ __forceinline__ void rgb2lab2x2(F2 rr, F2 rg, F2 rb,   // gt
                                           F2 gr, F2 gg, F2 gb,   // gen
                                           F2& L1, F2& A1, F2& B1,
                                           F2& L2, F2& A2, F2& B2) {
    F2 rl1 = vsrgb(rr), gl1 = vsrgb(rg), bl1 = vsrgb(rb);
    F2 rl2 = vsrgb(gr), gl2 = vsrgb(gg), bl2 = vsrgb(gb);
    // white point folded into matrix rows (x/0.95047, z/1.08883)
    F2 x1 = vfma(0.43395296f, rl1, vfma(0.37621626f, gl1, 0.18982646f * bl1));
    F2 y1 = vfma(0.212671f,  rl1, vfma(0.715160f,  gl1, 0.072169f  * bl1));
    F2 z1 = vfma(0.017757f,  rl1, vfma(0.10946953f, gl1, 0.87271810f * bl1));
    F2 x2 = vfma(0.43395296f, rl2, vfma(0.37621626f, gl2, 0.18982646f * bl2));
    F2 y2 = vfma(0.212671f,  rl2, vfma(0.715160f,  gl2, 0.072169f  * bl2));
    F2 z2 = vfma(0.017757f,  rl2, vfma(0.10946953f, gl2, 0.87271810f * bl2));
    F2 fx1 = vfxyz(x1), fy1 = vfxyz(y1), fz1 = vfxyz(z1);
    F2 fx2 = vfxyz(x2), fy2 = vfxyz(y2), fz2 = vfxyz(z2);
    L1 = vfma(116.0f, fy1, sp(-16.0f));
    A1 = 500.0f * (fx1 - fy1);
    B1 = 200.0f * (fy1 - fz1);
    L2 = vfma(116.0f, fy2, sp(-16.0f));
    A2 = 500.0f * (fx2 - fy2);
    B2 = 200.0f * (fy2 - fz2);
}

// CIEDE2000 for two pixel-pairs in lockstep; returns dE.x + dE.y
__device__ __forceinline__ float ciede2(F2 L1, F2 a1, F2 b1,
                                        F2 L2, F2 a2, F2 b2) {
    const float P25_7 = 6103515625.0f;        // 25^7

    F2 b1sq = b1 * b1, b2sq = b2 * b2;
    F2 C1 = vsqrt(vfma(a1, a1, b1sq));
    F2 C2 = vsqrt(vfma(a2, a2, b2sq));
    F2 Cbar = 0.5f * (C1 + C2);
    F2 c7 = vpow7(Cbar);
    F2 G1 = sp(1.5f) - 0.5f * vsqrt_ratio7(c7, P25_7);        // 1+G
    F2 a1p = a1 * G1;
    F2 a2p = a2 * G1;
    F2 C1p = vsqrt(vfma(a1p, a1p, b1sq));
    F2 C2p = vsqrt(vfma(a2p, a2p, b2sq));
    F2 CC  = C1p * C2p;

    // dHp = sign(cross)*sqrt(2*(CC - dot)); dot/cross from vector identity
    F2 dot   = vfma(a1p, a2p, b1 * b2);
    F2 cross = vfma(b2, a1p, -(a2p * b1));
    F2 dHp = vcopysign(vsqrt(vmaxs(2.0f * (CC - dot), 0.0f)), cross);

    F2 dLp = L2 - L1;
    F2 dCp = C2p - C1p;

    // hbar bisector = normalize(u1*C2p + u2*C1p); CC==0 cases are no-ops
    // (dHp=0 => tH=0 kills all hbar-dependent terms). n2=0 => sx=sy=0 =>
    // ch=sh=0 regardless of rsq(max) value.
    F2 sx = vfma(a1p, C2p, a2p * C1p);
    F2 sy = vfma(b1,  C2p, b2  * C1p);
    F2 n2 = vfma(sx, sx, sy * sy);
    F2 inv = vrsq(vmaxs(n2, 1e-30f));
    F2 ch = sx * inv, sh = sy * inv;          // cos(hbar), sin(hbar)

    // T by angle addition — no trig
    F2 c2v = vfma(2.0f * ch, ch, sp(-1.0f));
    F2 s2v = 2.0f * sh * ch;
    F2 c3v = vfma(c2v, ch, -(s2v * sh));
    F2 s3v = vfma(s2v, ch, c2v * sh);
    F2 c4v = vfma(2.0f * c2v, c2v, sp(-1.0f));
    F2 s4v = 2.0f * s2v * c2v;
    F2 T = sp(1.0f) - 0.17f * vfma(ch, 0.8660254037844387f, sh * 0.5f)
         + 0.24f * c2v
         + 0.32f * vfma(c3v, 0.9945218953682733f, s3v * (-0.10452846326765347f))
         - 0.20f * vfma(c4v, 0.45399049973954675f, s4v * 0.8910065241883679f);

    // Gaussian angle: td^2 = (phi_deg/25)^2 via asin^2 series in u2 (no sqrt)
    const float C275 = 0.08715574f, S275 = -0.9961947f;
    F2 cphi = vfma(ch, C275, sh * S275);          // cos(hbar - 275deg)
    F2 u2 = vmaxs(vfma(cphi, -0.5f, sp(0.5f)), 0.0f);
    F2 ser = vfma(u2, vfma(u2, vfma(u2, sp(0.11428571f), sp(0.17777778f)),
                           sp(0.33333333f)), sp(1.0f));
    F2 td2 = 21.00996f * (u2 * ser);               // (4.5836624^2)*asin^2(u)
    F2 dtheta = 30.0f * vexp2(-1.4426950408889634f * td2);

    F2 Lbar  = 0.5f * (L1 + L2);
    F2 Cbarp = 0.5f * (C1p + C2p);
    F2 Lm50 = Lbar - 50.0f;
    F2 q = Lm50 * Lm50;
    F2 Sl = vfma(0.015f * q, vrsq(q + 20.0f), sp(1.0f));
    F2 Sc = vfma(0.045f, Cbarp, sp(1.0f));
    F2 Sh = vfma(0.015f * Cbarp, T, sp(1.0f));

    F2 cb7 = vpow7(Cbarp);
    F2 Rc = 2.0f * vsqrt_ratio7(cb7, P25_7);
    // sin(2*dtheta deg): arg <= 1.047 rad; odd poly deg-5
    F2 xr = 0.034906585f * dtheta;
    F2 xr2 = xr * xr;
    F2 sin2dt = xr * vfma(xr2, vfma(xr2, sp(8.3333338e-3f), sp(-1.6666667e-1f)),
                          sp(1.0f));
    F2 Rt = -(Rc * sin2dt);

    F2 ScSh = Sc * Sh;
    F2 R3 = vrcp(Sl * ScSh);
    F2 tL = dLp * ScSh * R3;
    F2 tC = dCp * (Sl * Sh) * R3;
    F2 tH = dHp * (Sl * Sc) * R3;
    F2 s = vfma(tL, tL, vfma(tC, tC, vfma(tH, tH, Rt * tC * tH)));
    F2 dE = vsqrt(vmaxs(s, 0.0f));
    return fabsf(dE.x) + fabsf(dE.y);
}

// two pixel-pairs -> sum of their dE
__device__ __forceinline__ float de2(F2 gr, F2 gg, F2 gb,
                                     F2 rr, F2 rg, F2 rb) {
    F2 L1, A1, B1, L2, A2, B2;
    rgb2lab2x2(rr, rg, rb, gr, gg, gb, L1, A1, B1, L2, A2, B2);
    return ciede2(L1, A1, B1, L2, A2, B2);
}

// 4 pixels from 3 float4s per image: two lockstep pairs.
__device__ __forceinline__ float process4(const float4& g0, const float4& g1,
                                          const float4& g2, const float4& r0,
                                          const float4& r1, const float4& r2) {
    float acc;
    acc  = de2(mk2(g0.x, g0.w), mk2(g0.y, g1.x), mk2(g0.z, g1.y),
               mk2(r0.x, r0.w), mk2(r0.y, r1.x), mk2(r0.z, r1.y));
    acc += de2(mk2(g1.z, g2.y), mk2(g1.w, g2.z), mk2(g2.x, g2.w),
               mk2(r1.z, r2.y), mk2(r1.w, r2.z), mk2(r2.x, r2.w));
    return acc;
}

__device__ __forceinline__ void block_reduce_store(float acc, float* dst) {
    for (int off = 32; off > 0; off >>= 1) acc += __shfl_down(acc, off, 64);
    __shared__ float sm[4];
    int lane = threadIdx.x & 63;
    int wid  = threadIdx.x >> 6;
    if (lane == 0) sm[wid] = acc;
    __syncthreads();
    if (threadIdx.x == 0) *dst = sm[0] + sm[1] + sm[2] + sm[3];
}

// Exact-trip looped kernel, 1-deep register prefetch, waves_per_eu(2,4)
// (r11 optimum structure).
template <int NITER>
__global__ __attribute__((amdgpu_waves_per_eu(2, 4)))
__launch_bounds__(256) void de_main_fix(const float4* __restrict__ gen,
                                        const float4* __restrict__ gt,
                                        float* __restrict__ partial,
                                        int stride) {
    int t = blockIdx.x * 256 + threadIdx.x;
    float acc = 0.0f;

    float4 cg0 = gen[3 * t + 0], cg1 = gen[3 * t + 1], cg2 = gen[3 * t + 2];
    float4 cr0 = gt [3 * t + 0], cr1 = gt [3 * t + 1], cr2 = gt [3 * t + 2];

    #pragma unroll 1
    for (int it = 0; it < NITER - 1; ++it) {
        int tn = t + stride;
        float4 ng0 = gen[3 * tn + 0], ng1 = gen[3 * tn + 1], ng2 = gen[3 * tn + 2];
        float4 nr0 = gt [3 * tn + 0], nr1 = gt [3 * tn + 1], nr2 = gt [3 * tn + 2];
        acc += process4(cg0, cg1, cg2, cr0, cr1, cr2);
        cg0 = ng0; cg1 = ng1; cg2 = ng2;
        cr0 = nr0; cr1 = nr1; cr2 = nr2;
        t = tn;
    }
    acc += process4(cg0, cg1, cg2, cr0, cr1, cr2);

    block_reduce_store(acc, &partial[blockIdx.x]);
}

// Generic fallback (bounds-checked grid-stride), used only if sizes change.
__global__ __launch_bounds__(256) void de_main_gen(const float4* __restrict__ gen,
                                                   const float4* __restrict__ gt,
                                                   float* __restrict__ partial,
                                                   int ntrip) {
    int tid = blockIdx.x * blockDim.x + threadIdx.x;
    int stride = gridDim.x * blockDim.x;
    float acc = 0.0f;
    for (int t = tid; t < ntrip; t += stride) {
        float4 g0 = gen[3 * t + 0], g1 = gen[3 * t + 1], g2 = gen[3 * t + 2];
        float4 r0 = gt [3 * t + 0], r1 = gt [3 * t + 1], r2 = gt [3 * t + 2];
        acc += process4(g0, g1, g2, r0, r1, r2);
    }
    block_reduce_store(acc, &partial[blockIdx.x]);
}

__global__ __launch_bounds__(256) void de_final(const float* __restrict__ partial,
                                                float* __restrict__ out,
                                                int n, float inv_npix) {
    float acc = 0.0f;
    for (int i = threadIdx.x; i < n; i += 256) acc += partial[i];
    for (int off = 32; off > 0; off >>= 1) acc += __shfl_down(acc, off, 64);
    __shared__ float sm[4];
    int lane = threadIdx.x & 63;
    int wid  = threadIdx.x >> 6;
    if (lane == 0) sm[wid] = acc;
    __syncthreads();
    if (threadIdx.x == 0) out[0] = (sm[0] + sm[1] + sm[2] + sm[3]) * inv_npix;
}

extern "C" void kernel_launch(void* const* d_in, const int* in_sizes, int n_in,
                              void* d_out, int out_size, void* d_ws, size_t ws_size,
                              hipStream_t stream) {
    const float4* gen = (const float4*)d_in[0];  // genImage
    const float4* gt  = (const float4*)d_in[1];  // gtImage

    const int total_f = in_sizes[0];             // 25,165,824 floats
    const int ntrip   = total_f / 12;            // 4-pixel work items
    const int npix    = total_f / 3;

    float* partial = (float*)d_ws;
    const int blocks  = 2048;
    const int threads = blocks * 256;

    if (ntrip == threads * 4) {
        de_main_fix<4><<<blocks, 256, 0, stream>>>(gen, gt, partial, threads);
        de_final<<<1, 256, 0, stream>>>(partial, (float*)d_out,
                                        blocks, 1.0f / (float)npix);
    } else {
        de_main_gen<<<blocks, 256, 0, stream>>>(gen, gt, partial, ntrip);
        de_final<<<1, 256, 0, stream>>>(partial, (float*)d_out,
                                        blocks, 1.0f / (float)npix);
    }
}